// Round 1
// baseline (879.759 us; speedup 1.0000x reference)
//
#include <hip/hip_runtime.h>
#include <hip/hip_bf16.h>
#include <stdint.h>

#define N_NODES 100000
#define N_EDGES 1600000

// ---- workspace layout (bytes) ----
// h (bf16)  : N_NODES*128*2 = 25,600,000   @ 0
// sdeg (int): N_NODES*4     =    400,000   @ 25,600,000   (contiguous with rdeg for one memset)
// rdeg (int): N_NODES*4     =    400,000   @ 26,000,000
// row_ptr   : (N_NODES+1)*4 =    400,004   @ 26,400,000
// cursor    : N_NODES*4     =    400,000   @ 26,800,016
// bsums     : 256*4         =      1,024   @ 27,200,016
// edge_src  : N_EDGES*4     =  6,400,000   @ 27,201,056
// total ~ 33.6 MB
static const size_t OFF_H    = 0;
static const size_t OFF_SDEG = 25600000;
static const size_t OFF_RDEG = 26000000;
static const size_t OFF_ROWP = 26400000;
static const size_t OFF_CURS = 26800016;
static const size_t OFF_BSUM = 27200016;
static const size_t OFF_ESRC = 27201056;

// 1) degree counting: 3.2M int atomics over 100k counters (L2-resident)
__global__ __launch_bounds__(256) void deg_kernel(const int* __restrict__ snd,
                                                  const int* __restrict__ rcv,
                                                  int* __restrict__ sdeg,
                                                  int* __restrict__ rdeg) {
    int e = blockIdx.x * 256 + threadIdx.x;
    if (e < N_EDGES) {
        atomicAdd(&sdeg[snd[e]], 1);
        atomicAdd(&rdeg[rcv[e]], 1);
    }
}

// 2) block-level exclusive scan of rdeg -> row_ptr (partial) + block sums
__global__ __launch_bounds__(512) void scan1_kernel(const int* __restrict__ rdeg,
                                                    int* __restrict__ exscan,
                                                    int* __restrict__ bsums) {
    __shared__ int s[512];
    int t = threadIdx.x;
    int i = blockIdx.x * 512 + t;
    int v = (i < N_NODES) ? rdeg[i] : 0;
    s[t] = v;
    __syncthreads();
    #pragma unroll
    for (int off = 1; off < 512; off <<= 1) {
        int tv = (t >= off) ? s[t - off] : 0;
        __syncthreads();
        s[t] += tv;
        __syncthreads();
    }
    if (i < N_NODES) exscan[i] = s[t] - v;   // exclusive within block
    if (t == 511) bsums[blockIdx.x] = s[511];
}

// 3) scan the 196 block sums (single block)
__global__ __launch_bounds__(256) void scan2_kernel(int* __restrict__ bsums) {
    __shared__ int s[256];
    int t = threadIdx.x;
    int v = (t < 196) ? bsums[t] : 0;
    s[t] = v;
    __syncthreads();
    #pragma unroll
    for (int off = 1; off < 256; off <<= 1) {
        int tv = (t >= off) ? s[t - off] : 0;
        __syncthreads();
        s[t] += tv;
        __syncthreads();
    }
    if (t < 196) bsums[t] = s[t] - v;        // exclusive block offsets
}

// 4) add block offsets -> final row_ptr; init cursor = row_ptr
__global__ __launch_bounds__(512) void scan3_kernel(int* __restrict__ row_ptr,
                                                    const int* __restrict__ bsums,
                                                    int* __restrict__ cursor) {
    int i = blockIdx.x * 512 + threadIdx.x;
    if (i < N_NODES) {
        int r = row_ptr[i] + bsums[blockIdx.x];
        row_ptr[i] = r;
        cursor[i] = r;
    } else if (i == N_NODES) {
        row_ptr[N_NODES] = N_EDGES;
    }
}

// 5) GEMM: h[n][d] = (x[n]·W[:,d] + bias[d]) * rsqrt(max(sdeg[n],1)), stored bf16.
// Block: 64 nodes x 64 output dims, k staged in 2 chunks of 64. LDS ~33 KB -> 4 blocks/CU.
__global__ __launch_bounds__(256) void gemm_kernel(const float* __restrict__ x,
                                                   const float* __restrict__ W,
                                                   const float* __restrict__ bias,
                                                   const int* __restrict__ sdeg,
                                                   __hip_bfloat16* __restrict__ h) {
    __shared__ float Wl[64 * 64];   // W[kk+k][dh*64+d]
    __shared__ float xt[64 * 64];   // x[nbase+n][kk+c]
    __shared__ float bias_s[64];
    __shared__ float rs_s[64];

    int t = threadIdx.x;
    int nbase = (blockIdx.x >> 1) * 64;
    int dh = blockIdx.x & 1;
    int d = t & 63;
    int g = t >> 6;              // 0..3, each owns 16 nodes

    if (t < 64) {
        bias_s[t] = bias[dh * 64 + t];
        int n = nbase + t;
        float deg = (n < N_NODES) ? (float)sdeg[n] : 1.f;
        rs_s[t] = rsqrtf(fmaxf(deg, 1.f));
    }

    float acc[16];
    #pragma unroll
    for (int i = 0; i < 16; i++) acc[i] = 0.f;

    for (int kk = 0; kk < 128; kk += 64) {
        __syncthreads();
        #pragma unroll
        for (int j = 0; j < 16; j++) {
            int idx = t + j * 256;
            int k = idx >> 6, c = idx & 63;
            Wl[idx] = W[(kk + k) * 128 + dh * 64 + c];
        }
        #pragma unroll
        for (int j = 0; j < 16; j++) {
            int idx = t + j * 256;
            int n = idx >> 6, c = idx & 63;
            int gn = nbase + n;
            xt[idx] = (gn < N_NODES) ? x[gn * 128 + kk + c] : 0.f;
        }
        __syncthreads();
        const float4* xt4 = (const float4*)xt;
        #pragma unroll
        for (int k4 = 0; k4 < 16; k4++) {
            float w0 = Wl[(k4 * 4 + 0) * 64 + d];
            float w1 = Wl[(k4 * 4 + 1) * 64 + d];
            float w2 = Wl[(k4 * 4 + 2) * 64 + d];
            float w3 = Wl[(k4 * 4 + 3) * 64 + d];
            #pragma unroll
            for (int i = 0; i < 16; i++) {
                float4 xv = xt4[(g * 16 + i) * 16 + k4];   // wave-uniform -> LDS broadcast
                acc[i] = fmaf(xv.x, w0, acc[i]);
                acc[i] = fmaf(xv.y, w1, acc[i]);
                acc[i] = fmaf(xv.z, w2, acc[i]);
                acc[i] = fmaf(xv.w, w3, acc[i]);
            }
        }
    }

    #pragma unroll
    for (int i = 0; i < 16; i++) {
        int n = g * 16 + i;
        int gn = nbase + n;
        if (gn < N_NODES) {
            float val = (acc[i] + bias_s[d]) * rs_s[n];
            h[gn * 128 + dh * 64 + d] = __float2bfloat16(val);
        }
    }
}

// 6) bucket edges by receiver: edge_src[row_ptr[r] + slot] = sender
__global__ __launch_bounds__(256) void fill_kernel(const int* __restrict__ snd,
                                                   const int* __restrict__ rcv,
                                                   int* __restrict__ cursor,
                                                   int* __restrict__ esrc) {
    int e = blockIdx.x * 256 + threadIdx.x;
    if (e < N_EDGES) {
        int r = rcv[e];
        int pos = atomicAdd(&cursor[r], 1);
        esrc[pos] = snd[e];
    }
}

// 7) gather: one wave per node, lane covers dims (2*lane, 2*lane+1); coalesced
//    256B reads of bf16 h rows; fp32 accumulation; fused receiver-degree scale.
__global__ __launch_bounds__(256) void gather_kernel(const uint32_t* __restrict__ h2,
                                                     const int* __restrict__ row_ptr,
                                                     const int* __restrict__ rdeg,
                                                     const int* __restrict__ esrc,
                                                     float2* __restrict__ out2) {
    int node = blockIdx.x * 4 + (threadIdx.x >> 6);
    int lane = threadIdx.x & 63;
    int b = row_ptr[node];
    int e = row_ptr[node + 1];
    float a0 = 0.f, a1 = 0.f;
    for (int i = b; i < e; i++) {
        int s = esrc[i];                       // wave-uniform
        uint32_t v = h2[s * 64 + lane];        // 256B coalesced per wave
        a0 += __uint_as_float(v << 16);        // bf16 -> fp32 (element 2*lane)
        a1 += __uint_as_float(v & 0xffff0000u);// element 2*lane+1
    }
    float rs = rsqrtf(fmaxf((float)rdeg[node], 1.f));
    out2[node * 64 + lane] = make_float2(a0 * rs, a1 * rs);
}

extern "C" void kernel_launch(void* const* d_in, const int* in_sizes, int n_in,
                              void* d_out, int out_size, void* d_ws, size_t ws_size,
                              hipStream_t stream) {
    const float* x    = (const float*)d_in[0];
    const int*   snd  = (const int*)d_in[1];
    const int*   rcv  = (const int*)d_in[2];
    // d_in[3] = n_node scalar (constant 100000, unused)
    const float* W    = (const float*)d_in[4];
    const float* bias = (const float*)d_in[5];

    char* ws = (char*)d_ws;
    __hip_bfloat16* h = (__hip_bfloat16*)(ws + OFF_H);
    int* sdeg = (int*)(ws + OFF_SDEG);
    int* rdeg = (int*)(ws + OFF_RDEG);
    int* rowp = (int*)(ws + OFF_ROWP);
    int* curs = (int*)(ws + OFF_CURS);
    int* bsum = (int*)(ws + OFF_BSUM);
    int* esrc = (int*)(ws + OFF_ESRC);

    // zero both degree arrays (contiguous) — ws is poisoned 0xAA before every call
    hipMemsetAsync(ws + OFF_SDEG, 0, 2 * N_NODES * sizeof(int), stream);

    deg_kernel  <<<(N_EDGES + 255) / 256, 256, 0, stream>>>(snd, rcv, sdeg, rdeg);
    scan1_kernel<<<196, 512, 0, stream>>>(rdeg, rowp, bsum);
    scan2_kernel<<<1, 256, 0, stream>>>(bsum);
    scan3_kernel<<<196, 512, 0, stream>>>(rowp, bsum, curs);
    gemm_kernel <<<((N_NODES + 63) / 64) * 2, 256, 0, stream>>>(x, W, bias, sdeg, h);
    fill_kernel <<<(N_EDGES + 255) / 256, 256, 0, stream>>>(snd, rcv, curs, esrc);
    gather_kernel<<<N_NODES / 4, 256, 0, stream>>>((const uint32_t*)h, rowp, rdeg, esrc, (float2*)d_out);
}

// Round 2
// 447.730 us; speedup vs baseline: 1.9649x; 1.9649x over previous
//
#include <hip/hip_runtime.h>
#include <hip/hip_bf16.h>
#include <stdint.h>

#define N_NODES 100000
#define N_EDGES 1600000

// ---- workspace layout (bytes) ----
static const size_t OFF_H    = 0;            // h bf16: 100000*128*2 = 25,600,000
static const size_t OFF_SDEG = 25600000;     // int 400,000
static const size_t OFF_RDEG = 26000000;     // int 400,000
static const size_t OFF_ROWP = 26400000;     // int 400,004
static const size_t OFF_CURS = 26800016;     // int 400,000
static const size_t OFF_BSUM = 27200016;     // int 1,024
static const size_t OFF_ESRC = 27201056;     // int 6,400,000

using short8 = __attribute__((ext_vector_type(8))) short;
using f32x4  = __attribute__((ext_vector_type(4))) float;

// fp32 -> bf16 bits, round-to-nearest-even (finite inputs)
static __device__ __forceinline__ short f2bf(float f) {
    uint32_t u = __float_as_uint(f);
    uint32_t r = (u + 0x7fffu + ((u >> 16) & 1u)) >> 16;
    return (short)r;
}

// 1) degree counting
__global__ __launch_bounds__(256) void deg_kernel(const int* __restrict__ snd,
                                                  const int* __restrict__ rcv,
                                                  int* __restrict__ sdeg,
                                                  int* __restrict__ rdeg) {
    int e = blockIdx.x * 256 + threadIdx.x;
    if (e < N_EDGES) {
        atomicAdd(&sdeg[snd[e]], 1);
        atomicAdd(&rdeg[rcv[e]], 1);
    }
}

// 2) block-level exclusive scan of rdeg -> row_ptr (partial) + block sums
__global__ __launch_bounds__(512) void scan1_kernel(const int* __restrict__ rdeg,
                                                    int* __restrict__ exscan,
                                                    int* __restrict__ bsums) {
    __shared__ int s[512];
    int t = threadIdx.x;
    int i = blockIdx.x * 512 + t;
    int v = (i < N_NODES) ? rdeg[i] : 0;
    s[t] = v;
    __syncthreads();
    #pragma unroll
    for (int off = 1; off < 512; off <<= 1) {
        int tv = (t >= off) ? s[t - off] : 0;
        __syncthreads();
        s[t] += tv;
        __syncthreads();
    }
    if (i < N_NODES) exscan[i] = s[t] - v;
    if (t == 511) bsums[blockIdx.x] = s[511];
}

// 3) scan the 196 block sums
__global__ __launch_bounds__(256) void scan2_kernel(int* __restrict__ bsums) {
    __shared__ int s[256];
    int t = threadIdx.x;
    int v = (t < 196) ? bsums[t] : 0;
    s[t] = v;
    __syncthreads();
    #pragma unroll
    for (int off = 1; off < 256; off <<= 1) {
        int tv = (t >= off) ? s[t - off] : 0;
        __syncthreads();
        s[t] += tv;
        __syncthreads();
    }
    if (t < 196) bsums[t] = s[t] - v;
}

// 4) final row_ptr; cursor = row_ptr
__global__ __launch_bounds__(512) void scan3_kernel(int* __restrict__ row_ptr,
                                                    const int* __restrict__ bsums,
                                                    int* __restrict__ cursor) {
    int i = blockIdx.x * 512 + threadIdx.x;
    if (i < N_NODES) {
        int r = row_ptr[i] + bsums[blockIdx.x];
        row_ptr[i] = r;
        cursor[i] = r;
    } else if (i == N_NODES) {
        row_ptr[N_NODES] = N_EDGES;
    }
}

// 5) MFMA GEMM: h[n][d] = bf16((x[n]·W[:,d] + bias[d]) * rsqrt(max(sdeg[n],1)))
// Block: 128 nodes x 128 dims, 4 waves. A frags direct from global (x has no
// cross-block reuse); W staged once to LDS in B-fragment layout (32 KB).
// mfma_f32_16x16x32_bf16: A[m=lane&15][k=quad*8+j]; B[k=quad*8+j][n=lane&15];
// D col=lane&15, row=quad*4+reg.
__global__ __launch_bounds__(256) void gemm_mfma_kernel(const float* __restrict__ x,
                                                        const float* __restrict__ W,
                                                        const float* __restrict__ bias,
                                                        const int* __restrict__ sdeg,
                                                        short* __restrict__ h) {
    __shared__ __align__(16) short Wl[32 * 64 * 8];   // [frag s*8+c][lane][j]
    __shared__ float bias_s[128];

    const int t = threadIdx.x;
    const int lane = t & 63;
    const int wv = t >> 6;          // wave 0..3
    const int quad = lane >> 4;     // 0..3
    const int mcol = lane & 15;

    // ---- stage W (bf16, fragment layout). thread t -> frags wv+4*i, slot lane
    #pragma unroll
    for (int i = 0; i < 8; i++) {
        int f = wv + 4 * i;             // 0..31
        int s = f >> 3;                 // k-step
        int c = f & 7;                  // n-chunk
        int krow = s * 32 + quad * 8;
        int ncol = c * 16 + mcol;
        short8 wf;
        #pragma unroll
        for (int j = 0; j < 8; j++)
            wf[j] = f2bf(W[(krow + j) * 128 + ncol]);
        *(short8*)&Wl[(f * 64 + lane) * 8] = wf;
    }
    if (t < 128) bias_s[t] = bias[t];

    // ---- A fragments from global: wave owns 32 nodes (2 m-frags), 4 k-steps
    const int node0 = blockIdx.x * 128 + wv * 32;
    short8 afrag[2][4];
    #pragma unroll
    for (int mf = 0; mf < 2; mf++) {
        int node = node0 + mf * 16 + mcol;
        bool ok = node < N_NODES;
        const float* xr = x + (size_t)(ok ? node : 0) * 128;
        #pragma unroll
        for (int s = 0; s < 4; s++) {
            int k0 = s * 32 + quad * 8;
            f32x4 v0 = ok ? *(const f32x4*)(xr + k0)     : f32x4{0.f,0.f,0.f,0.f};
            f32x4 v1 = ok ? *(const f32x4*)(xr + k0 + 4) : f32x4{0.f,0.f,0.f,0.f};
            short8 af;
            #pragma unroll
            for (int j = 0; j < 4; j++) {
                af[j]     = f2bf(v0[j]);
                af[4 + j] = f2bf(v1[j]);
            }
            afrag[mf][s] = af;
        }
    }

    __syncthreads();

    // ---- K fully unrolled: 64 MFMAs/wave, 32 ds_read_b128/wave
    f32x4 acc[2][8];
    #pragma unroll
    for (int mf = 0; mf < 2; mf++)
        #pragma unroll
        for (int c = 0; c < 8; c++)
            acc[mf][c] = f32x4{0.f, 0.f, 0.f, 0.f};

    #pragma unroll
    for (int s = 0; s < 4; s++) {
        #pragma unroll
        for (int c = 0; c < 8; c++) {
            short8 bfrag = *(const short8*)&Wl[((s * 8 + c) * 64 + lane) * 8];
            acc[0][c] = __builtin_amdgcn_mfma_f32_16x16x32_bf16(afrag[0][s], bfrag, acc[0][c], 0, 0, 0);
            acc[1][c] = __builtin_amdgcn_mfma_f32_16x16x32_bf16(afrag[1][s], bfrag, acc[1][c], 0, 0, 0);
        }
    }

    // ---- epilogue: bias + sender-degree scale, store bf16
    float rsv[2][4];
    #pragma unroll
    for (int mf = 0; mf < 2; mf++)
        #pragma unroll
        for (int r = 0; r < 4; r++) {
            int nd = node0 + mf * 16 + quad * 4 + r;
            float dg = (nd < N_NODES) ? (float)sdeg[nd] : 1.f;
            rsv[mf][r] = rsqrtf(fmaxf(dg, 1.f));
        }

    #pragma unroll
    for (int mf = 0; mf < 2; mf++)
        #pragma unroll
        for (int c = 0; c < 8; c++) {
            float bval = bias_s[c * 16 + mcol];
            #pragma unroll
            for (int r = 0; r < 4; r++) {
                int nd = node0 + mf * 16 + quad * 4 + r;
                if (nd < N_NODES)
                    h[(size_t)nd * 128 + c * 16 + mcol] =
                        f2bf((acc[mf][c][r] + bval) * rsv[mf][r]);
            }
        }
}

// 6) bucket edges by receiver
__global__ __launch_bounds__(256) void fill_kernel(const int* __restrict__ snd,
                                                   const int* __restrict__ rcv,
                                                   int* __restrict__ cursor,
                                                   int* __restrict__ esrc) {
    int e = blockIdx.x * 256 + threadIdx.x;
    if (e < N_EDGES) {
        int r = rcv[e];
        int pos = atomicAdd(&cursor[r], 1);
        esrc[pos] = snd[e];
    }
}

// 7) gather: one wave per node; 4-wide edge unroll for memory-level parallelism
__global__ __launch_bounds__(256) void gather_kernel(const uint32_t* __restrict__ h2,
                                                     const int* __restrict__ row_ptr,
                                                     const int* __restrict__ rdeg,
                                                     const int* __restrict__ esrc,
                                                     float2* __restrict__ out2) {
    int node = blockIdx.x * 4 + (threadIdx.x >> 6);
    int lane = threadIdx.x & 63;
    int b = row_ptr[node];
    int e = row_ptr[node + 1];
    float a0 = 0.f, a1 = 0.f;
    int i = b;
    for (; i + 4 <= e; i += 4) {
        int s0 = esrc[i + 0], s1 = esrc[i + 1], s2 = esrc[i + 2], s3 = esrc[i + 3];
        uint32_t v0 = h2[(size_t)s0 * 64 + lane];
        uint32_t v1 = h2[(size_t)s1 * 64 + lane];
        uint32_t v2 = h2[(size_t)s2 * 64 + lane];
        uint32_t v3 = h2[(size_t)s3 * 64 + lane];
        a0 += __uint_as_float(v0 << 16) + __uint_as_float(v1 << 16)
            + __uint_as_float(v2 << 16) + __uint_as_float(v3 << 16);
        a1 += __uint_as_float(v0 & 0xffff0000u) + __uint_as_float(v1 & 0xffff0000u)
            + __uint_as_float(v2 & 0xffff0000u) + __uint_as_float(v3 & 0xffff0000u);
    }
    for (; i < e; i++) {
        int s = esrc[i];
        uint32_t v = h2[(size_t)s * 64 + lane];
        a0 += __uint_as_float(v << 16);
        a1 += __uint_as_float(v & 0xffff0000u);
    }
    float rs = rsqrtf(fmaxf((float)rdeg[node], 1.f));
    out2[(size_t)node * 64 + lane] = make_float2(a0 * rs, a1 * rs);
}

extern "C" void kernel_launch(void* const* d_in, const int* in_sizes, int n_in,
                              void* d_out, int out_size, void* d_ws, size_t ws_size,
                              hipStream_t stream) {
    const float* x    = (const float*)d_in[0];
    const int*   snd  = (const int*)d_in[1];
    const int*   rcv  = (const int*)d_in[2];
    const float* W    = (const float*)d_in[4];
    const float* bias = (const float*)d_in[5];

    char* ws = (char*)d_ws;
    short* h  = (short*)(ws + OFF_H);
    int* sdeg = (int*)(ws + OFF_SDEG);
    int* rdeg = (int*)(ws + OFF_RDEG);
    int* rowp = (int*)(ws + OFF_ROWP);
    int* curs = (int*)(ws + OFF_CURS);
    int* bsum = (int*)(ws + OFF_BSUM);
    int* esrc = (int*)(ws + OFF_ESRC);

    hipMemsetAsync(ws + OFF_SDEG, 0, 2 * N_NODES * sizeof(int), stream);

    deg_kernel   <<<(N_EDGES + 255) / 256, 256, 0, stream>>>(snd, rcv, sdeg, rdeg);
    scan1_kernel <<<196, 512, 0, stream>>>(rdeg, rowp, bsum);
    scan2_kernel <<<1, 256, 0, stream>>>(bsum);
    scan3_kernel <<<196, 512, 0, stream>>>(rowp, bsum, curs);
    gemm_mfma_kernel<<<(N_NODES + 127) / 128, 256, 0, stream>>>(x, W, bias, sdeg, h);
    fill_kernel  <<<(N_EDGES + 255) / 256, 256, 0, stream>>>(snd, rcv, curs, esrc);
    gather_kernel<<<N_NODES / 4, 256, 0, stream>>>((const uint32_t*)h, rowp, rdeg, esrc, (float2*)d_out);
}